// Round 1
// baseline (137.026 us; speedup 1.0000x reference)
//
#include <hip/hip_runtime.h>
#include <math.h>

#define NB 32
#define NS 384
#define NLM 543
#define NL 67
#define NF 743

// SEL = FACE(19) + [468..488](21) + [522..542](21) + [11..16](6) = 67
__constant__ int d_SEL[NL] = {
    33, 133, 362, 263, 61, 291, 199, 419, 17, 84, 314, 405, 320, 307, 375, 321, 308, 324, 318,
    468, 469, 470, 471, 472, 473, 474, 475, 476, 477, 478, 479, 480, 481, 482, 483, 484, 485, 486, 487, 488,
    522, 523, 524, 525, 526, 527, 528, 529, 530, 531, 532, 533, 534, 535, 536, 537, 538, 539, 540, 541, 542,
    11, 12, 13, 14, 15, 16
};

__device__ __forceinline__ float fin(float v) { return isfinite(v) ? v : 0.0f; }

// Feature layout per (b,s) row of 743 floats:
// c:[0,134) vel:[134,268) acc:[268,402) vm:[402,469) am:[469,536)
// cum:[536,603) ang:[603,670) dchg:[670,737) dists:[737,743)

// K1: one wave (64 lanes) per (b,s). Gather 67 landmarks, normalize, write c + dists.
__global__ __launch_bounds__(256) void k_norm(const float* __restrict__ x,
                                              float* __restrict__ out) {
    const int wave = threadIdx.x >> 6;
    const int lane = threadIdx.x & 63;
    const int bs = blockIdx.x * 4 + wave;           // grid sized exactly: bs < 12288
    const float* __restrict__ xr = x + (size_t)bs * (NLM * 3);

    // lane owns landmark `lane` (always <67) and, for lanes 0..2, landmark lane+64
    const int lm0 = lane;
    const bool has1 = (lane < 3);
    const int lm1 = lane + 64;

    int o0 = d_SEL[lm0] * 3;
    float a0x = xr[o0], a0y = xr[o0 + 1];
    float a1x = 0.f, a1y = 0.f;
    if (has1) { int o1 = d_SEL[lm1] * 3; a1x = xr[o1]; a1y = xr[o1 + 1]; }

    // per-coordinate mean over 67 landmarks
    float sx = a0x + a1x, sy = a0y + a1y;
    #pragma unroll
    for (int off = 32; off; off >>= 1) { sx += __shfl_xor(sx, off); sy += __shfl_xor(sy, off); }
    const float mx = sx * (1.0f / 67.0f), my = sy * (1.0f / 67.0f);

    float c0x = a0x - mx, c0y = a0y - my;
    float c1x = a1x - mx, c1y = a1y - my;

    // sample std (ddof=1) over all 134 centered values
    float ss = c0x * c0x + c0y * c0y + (has1 ? (c1x * c1x + c1y * c1y) : 0.f);
    #pragma unroll
    for (int off = 32; off; off >>= 1) ss += __shfl_xor(ss, off);
    const float stdv = sqrtf(ss * (1.0f / 133.0f));
    const float scale = (stdv > 1e-6f) ? (1.0f / stdv) : 1.0f;

    c0x *= scale; c0y *= scale; c1x *= scale; c1y *= scale;

    float* __restrict__ row = out + (size_t)bs * NF;
    row[2 * lm0]     = fin(c0x);
    row[2 * lm0 + 1] = fin(c0y);
    if (has1) { row[2 * lm1] = fin(c1x); row[2 * lm1 + 1] = fin(c1y); }

    // 6 pairwise dists among selected landmarks 0..4 (held in lanes 0..4)
    const int PI_[6] = {0, 0, 1, 1, 2, 2};
    const int PJ_[6] = {1, 2, 2, 3, 3, 4};
    const int p = (lane < 6) ? lane : 0;
    float xi = __shfl(c0x, PI_[p]); float yi = __shfl(c0y, PI_[p]);
    float xj = __shfl(c0x, PJ_[p]); float yj = __shfl(c0y, PJ_[p]);
    if (lane < 6) {
        float dx = xi - xj + 1e-8f, dy = yi - yj + 1e-8f;
        row[737 + lane] = fin(sqrtf(dx * dx + dy * dy));
    }
}

// K2: one thread per (b,s,lm). Reads c rows s, s-1, s-2 from out; writes vel/acc/vm/am/ang/dchg.
__global__ __launch_bounds__(256) void k_dyn(float* __restrict__ out) {
    const unsigned tid = blockIdx.x * 256u + threadIdx.x;   // < 823296 exact
    const unsigned bs = tid / NL;
    const int lm = (int)(tid - bs * NL);
    const int s = (int)(bs % NS);

    float* __restrict__ row = out + (size_t)bs * NF;
    const float cx = row[2 * lm], cy = row[2 * lm + 1];
    float px = 0.f, py = 0.f, qx = 0.f, qy = 0.f;
    if (s >= 1) { px = row[2 * lm - NF];     py = row[2 * lm + 1 - NF]; }
    if (s >= 2) { qx = row[2 * lm - 2 * NF]; qy = row[2 * lm + 1 - 2 * NF]; }

    const float vx = (s >= 1) ? (cx - px) : 0.f;
    const float vy = (s >= 1) ? (cy - py) : 0.f;
    // acc = vel[s] - vel[s-1], match reference fp ordering
    const float v1x = px - qx, v1y = py - qy;
    const float ax = (s >= 2) ? (vx - v1x) : 0.f;
    const float ay = (s >= 2) ? (vy - v1y) : 0.f;

    const float wx = vx + 1e-8f, wy = vy + 1e-8f;
    const float vm = sqrtf(wx * wx + wy * wy);
    const float ux = ax + 1e-8f, uy = ay + 1e-8f;
    const float am = sqrtf(ux * ux + uy * uy);

    const float ang = atan2f(vy + 1e-8f, vx + 1e-8f);
    float dchg = 0.f;
    if (s >= 2) {
        const float ang1 = atan2f(v1y + 1e-8f, v1x + 1e-8f);
        dchg = ang - ang1;
    }

    row[134 + 2 * lm] = vx;
    row[135 + 2 * lm] = vy;
    row[268 + 2 * lm] = ax;
    row[269 + 2 * lm] = ay;
    row[402 + lm] = vm;
    row[469 + lm] = am;
    row[603 + lm] = fin(ang);
    row[670 + lm] = fin(dchg);
}

// K3: one wave per (b,lm). Exclusive cumsum of vm over the 384-step sequence,
// chunked 6x64 with a wave-level inclusive scan per chunk + running carry.
__global__ __launch_bounds__(256) void k_cum(float* __restrict__ out) {
    const int gw = (int)((blockIdx.x * 256u + threadIdx.x) >> 6);   // wave id < 2144 exact
    const int lane = threadIdx.x & 63;
    const int b = gw / NL;
    const int lm = gw - b * NL;

    float carry = 0.f;
    #pragma unroll
    for (int k = 0; k < 6; ++k) {
        const int t = k * 64 + lane;
        const size_t idx = ((size_t)(b * NS + t)) * NF;
        const float v = out[idx + 402 + lm];
        float incl = v;
        #pragma unroll
        for (int off = 1; off < 64; off <<= 1) {
            float y = __shfl_up(incl, off);
            if (lane >= off) incl += y;
        }
        out[idx + 536 + lm] = fin(carry + (incl - v));   // exclusive prefix
        carry += __shfl(incl, 63);
    }
}

extern "C" void kernel_launch(void* const* d_in, const int* in_sizes, int n_in,
                              void* d_out, int out_size, void* d_ws, size_t ws_size,
                              hipStream_t stream) {
    const float* x = (const float*)d_in[0];
    float* out = (float*)d_out;

    // K1: 12288 (b,s) rows, 1 wave each, 4 waves/block
    k_norm<<<(NB * NS) / 4, 256, 0, stream>>>(x, out);
    // K2: 823296 threads = 3216 * 256 exact
    k_dyn<<<(NB * NS * NL) / 256, 256, 0, stream>>>(out);
    // K3: 2144 waves = 536 blocks * 4 waves exact
    k_cum<<<(NB * NL) / 4, 256, 0, stream>>>(out);
}

// Round 2
// 136.495 us; speedup vs baseline: 1.0039x; 1.0039x over previous
//
#include <hip/hip_runtime.h>
#include <math.h>

#define NB 32
#define NS 384
#define NLM 543
#define NL 67
#define NF 743

// SEL = FACE(19) + [468..488](21) + [522..542](21) + [11..16](6) = 67
__constant__ int d_SEL[NL] = {
    33, 133, 362, 263, 61, 291, 199, 419, 17, 84, 314, 405, 320, 307, 375, 321, 308, 324, 318,
    468, 469, 470, 471, 472, 473, 474, 475, 476, 477, 478, 479, 480, 481, 482, 483, 484, 485, 486, 487, 488,
    522, 523, 524, 525, 526, 527, 528, 529, 530, 531, 532, 533, 534, 535, 536, 537, 538, 539, 540, 541, 542,
    11, 12, 13, 14, 15, 16
};

__device__ __forceinline__ float fin(float v) { return isfinite(v) ? v : 0.0f; }

// Feature layout per (b,s) row of 743 floats:
// c:[0,134) vel:[134,268) acc:[268,402) vm:[402,469) am:[469,536)
// cum:[536,603) ang:[603,670) dchg:[670,737) dists:[737,743)

// Gather + normalize one (b,s) row of x into centered/scaled coords.
// Lane owns landmark `lane`; lanes 0..2 additionally own landmark lane+64.
__device__ __forceinline__ void gather_norm(const float* __restrict__ xr,
                                            int lane, int o0, int o1, bool has1,
                                            float& c0x, float& c0y,
                                            float& c1x, float& c1y) {
    float a0x = xr[o0], a0y = xr[o0 + 1];
    float a1x = 0.f, a1y = 0.f;
    if (has1) { a1x = xr[o1]; a1y = xr[o1 + 1]; }

    float sx = a0x + a1x, sy = a0y + a1y;
    #pragma unroll
    for (int off = 32; off; off >>= 1) { sx += __shfl_xor(sx, off); sy += __shfl_xor(sy, off); }
    const float mx = sx * (1.0f / 67.0f), my = sy * (1.0f / 67.0f);

    c0x = a0x - mx; c0y = a0y - my;
    c1x = a1x - mx; c1y = a1y - my;

    float ss = c0x * c0x + c0y * c0y + (has1 ? (c1x * c1x + c1y * c1y) : 0.f);
    #pragma unroll
    for (int off = 32; off; off >>= 1) ss += __shfl_xor(ss, off);
    const float stdv = sqrtf(ss * (1.0f / 133.0f));
    const float scale = (stdv > 1e-6f) ? (1.0f / stdv) : 1.0f;

    c0x *= scale; c0y *= scale; c1x *= scale; c1y *= scale;
}

// K_main: one wave per (b,s). Recomputes c for rows s, s-1, s-2 (bitwise-identical
// fp ops => identical to a staged c), then writes everything except cum.
// Also writes vm transposed to stage[b][lm][s] for the coalesced scan kernel.
__global__ __launch_bounds__(256) void k_main(const float* __restrict__ x,
                                              float* __restrict__ out,
                                              float* __restrict__ vmstage) {
    const int wave = threadIdx.x >> 6;
    const int lane = threadIdx.x & 63;
    const int bs = blockIdx.x * 4 + wave;          // < 12288 exact
    const int s = bs % NS;
    const int b = bs / NS;

    const int lm0 = lane;
    const bool has1 = (lane < 3);
    const int lm1 = lane + 64;
    const int o0 = d_SEL[lm0] * 3;
    const int o1 = has1 ? d_SEL[lm1] * 3 : 0;

    const float* __restrict__ xr = x + (size_t)bs * (NLM * 3);

    float c0x, c0y, c1x, c1y;           // row s
    gather_norm(xr, lane, o0, o1, has1, c0x, c0y, c1x, c1y);

    float p0x = 0.f, p0y = 0.f, p1x = 0.f, p1y = 0.f;   // row s-1
    if (s >= 1) gather_norm(xr - NLM * 3, lane, o0, o1, has1, p0x, p0y, p1x, p1y);
    float q0x = 0.f, q0y = 0.f, q1x = 0.f, q1y = 0.f;   // row s-2
    if (s >= 2) gather_norm(xr - 2 * NLM * 3, lane, o0, o1, has1, q0x, q0y, q1x, q1y);

    float* __restrict__ row = out + (size_t)bs * NF;

    // ---- per-landmark dynamics, computed for (lm0) and optionally (lm1) ----
    #pragma unroll
    for (int half = 0; half < 2; ++half) {
        if (half == 1 && !has1) break;
        const int lm  = half ? lm1 : lm0;
        const float cx = half ? c1x : c0x, cy = half ? c1y : c0y;
        const float px = half ? p1x : p0x, py = half ? p1y : p0y;
        const float qx = half ? q1x : q0x, qy = half ? q1y : q0y;

        const float vx = (s >= 1) ? (cx - px) : 0.f;
        const float vy = (s >= 1) ? (cy - py) : 0.f;
        const float v1x = px - qx, v1y = py - qy;        // vel[s-1] (valid when s>=2)
        const float ax = (s >= 2) ? (vx - v1x) : 0.f;
        const float ay = (s >= 2) ? (vy - v1y) : 0.f;

        const float wx = vx + 1e-8f, wy = vy + 1e-8f;
        const float vm = sqrtf(wx * wx + wy * wy);
        const float ux = ax + 1e-8f, uy = ay + 1e-8f;
        const float am = sqrtf(ux * ux + uy * uy);

        const float ang = atan2f(vy + 1e-8f, vx + 1e-8f);
        float dchg = 0.f;
        if (s >= 2) dchg = ang - atan2f(v1y + 1e-8f, v1x + 1e-8f);

        row[2 * lm]       = fin(cx);
        row[2 * lm + 1]   = fin(cy);
        row[134 + 2 * lm] = vx;
        row[135 + 2 * lm] = vy;
        row[268 + 2 * lm] = ax;
        row[269 + 2 * lm] = ay;
        row[402 + lm]     = vm;
        row[469 + lm]     = am;
        row[603 + lm]     = fin(ang);
        row[670 + lm]     = fin(dchg);
        vmstage[((size_t)b * NL + lm) * NS + s] = vm;
    }

    // 6 pairwise dists among selected landmarks 0..4 (held in lanes 0..4)
    const int PI_[6] = {0, 0, 1, 1, 2, 2};
    const int PJ_[6] = {1, 2, 2, 3, 3, 4};
    const int p = (lane < 6) ? lane : 0;
    float xi = __shfl(c0x, PI_[p]); float yi = __shfl(c0y, PI_[p]);
    float xj = __shfl(c0x, PJ_[p]); float yj = __shfl(c0y, PJ_[p]);
    if (lane < 6) {
        float dx = xi - xj + 1e-8f, dy = yi - yj + 1e-8f;
        row[737 + lane] = fin(sqrtf(dx * dx + dy * dy));
    }
}

// K_scan: one wave per (b,lm). Exclusive cumsum of vm over the 384-step
// sequence; coalesced reads from the transposed stage, strided writes to out
// (absorbed by L2 — cum-region line working set ~4.6 MB).
__global__ __launch_bounds__(256) void k_scan(const float* __restrict__ vmstage,
                                              float* __restrict__ out) {
    const int gw = (int)((blockIdx.x * 256u + threadIdx.x) >> 6);   // < 2144 exact
    const int lane = threadIdx.x & 63;
    const int b = gw / NL;
    const int lm = gw - b * NL;
    const float* __restrict__ src = vmstage + (size_t)gw * NS;

    float carry = 0.f;
    #pragma unroll
    for (int k = 0; k < 6; ++k) {
        const int t = k * 64 + lane;
        const float v = src[t];
        float incl = v;
        #pragma unroll
        for (int off = 1; off < 64; off <<= 1) {
            float y = __shfl_up(incl, off);
            if (lane >= off) incl += y;
        }
        out[((size_t)(b * NS + t)) * NF + 536 + lm] = fin(carry + (incl - v));
        carry += __shfl(incl, 63);
    }
}

extern "C" void kernel_launch(void* const* d_in, const int* in_sizes, int n_in,
                              void* d_out, int out_size, void* d_ws, size_t ws_size,
                              hipStream_t stream) {
    const float* x = (const float*)d_in[0];
    float* out = (float*)d_out;
    float* vmstage = (float*)d_ws;   // 32*67*384*4 = 3.3 MB

    k_main<<<(NB * NS) / 4, 256, 0, stream>>>(x, out, vmstage);
    k_scan<<<(NB * NL) / 4, 256, 0, stream>>>(vmstage, out);
}